// Round 2
// baseline (1489.455 us; speedup 1.0000x reference)
//
#include <hip/hip_runtime.h>
#include <hip/hip_bf16.h>
#include <math.h>

// Problem constants
#define NN 8000   // nodes
#define LL 32     // labels (feat cols, M cols)
#define KK 16     // tensor neurons
#define BB 16     // bottleneck
#define DD 64     // 2L

// Workspace layout (floats):
//   [0      .. 8000)    c1a = colsum(adj1)
//   [8000   .. 16000)   c1b = colsum(adj2)
//   [16000  .. 16192)   g: g1_01 g1_h1 g1_h2 g2_01 g2_h1 g2_h2 (6 x 32)
//   [16192  .. 272192)  M1 = adj1 @ feat1   [8000][32]
//   [272192 .. 528192)  M2 = adj2 @ feat2   [8000][32]
#define WS_C1A 0
#define WS_C1B 8000
#define WS_G   16000
#define WS_M1  16192
#define WS_M2  (WS_M1 + NN * LL)
#define WS_ZERO_N 16192   // only c1a, c1b, g need zeroing (M written fully)

#define CHUNK_K 256       // F rows staged per chunk
#define F_PAD   36        // padded LDS row stride (floats), 16B-aligned, breaks bank alias

__global__ void zero_kernel(float* __restrict__ p, int n) {
    int i = blockIdx.x * 256 + threadIdx.x;
    if (i < n) p[i] = 0.0f;
}

// Math for one 64-k iteration: per-thread 8 rows x 8 l-values, 4 k each.
// acc[r][e] += A[row r][k(j)] * F[k(j)][lg*8+e];  csum[j] += sum_r A (colsum partial)
__device__ __forceinline__ void iter_math(const float4* a, const float* f_lds,
                                          int kcoff, int lg,
                                          float acc[8][8], float4& csum) {
    float4 f0[4], f1[4];
#pragma unroll
    for (int j = 0; j < 4; ++j) {
        const float* fp = f_lds + (kcoff + j) * F_PAD + lg * 8;
        f0[j] = *(const float4*)fp;
        f1[j] = *(const float4*)(fp + 4);
    }
#pragma unroll
    for (int r = 0; r < 8; ++r) {
        float4 v = a[r];
        csum.x += v.x; csum.y += v.y; csum.z += v.z; csum.w += v.w;
        acc[r][0] += v.x*f0[0].x; acc[r][1] += v.x*f0[0].y; acc[r][2] += v.x*f0[0].z; acc[r][3] += v.x*f0[0].w;
        acc[r][4] += v.x*f1[0].x; acc[r][5] += v.x*f1[0].y; acc[r][6] += v.x*f1[0].z; acc[r][7] += v.x*f1[0].w;
        acc[r][0] += v.y*f0[1].x; acc[r][1] += v.y*f0[1].y; acc[r][2] += v.y*f0[1].z; acc[r][3] += v.y*f0[1].w;
        acc[r][4] += v.y*f1[1].x; acc[r][5] += v.y*f1[1].y; acc[r][6] += v.y*f1[1].z; acc[r][7] += v.y*f1[1].w;
        acc[r][0] += v.z*f0[2].x; acc[r][1] += v.z*f0[2].y; acc[r][2] += v.z*f0[2].z; acc[r][3] += v.z*f0[2].w;
        acc[r][4] += v.z*f1[2].x; acc[r][5] += v.z*f1[2].y; acc[r][6] += v.z*f1[2].z; acc[r][7] += v.z*f1[2].w;
        acc[r][0] += v.w*f0[3].x; acc[r][1] += v.w*f0[3].y; acc[r][2] += v.w*f0[3].z; acc[r][3] += v.w*f0[3].w;
        acc[r][4] += v.w*f1[3].x; acc[r][5] += v.w*f1[3].y; acc[r][6] += v.w*f1[3].z; acc[r][7] += v.w*f1[3].w;
    }
}

// Fused single pass over A: M = A @ F  AND  c1 = colsum(A).
// block = 512 threads = 8 waves; wave owns 8 rows -> block owns 64 rows.
// grid = 250: bx<125 -> matrix 1 rows 64*bx; else matrix 2.
// Wave lane layout: kpos = lane&15 (16 k-positions x 4 k), lg = lane>>4 (4 l-groups x 8 l).
// A read direct from global (float4, coalescer merges the 4-way lg redundancy).
// F chunk-staged in LDS (padded rows). c1 accumulated in LDS via ds atomics,
// flushed once per block with global atomicAdd.
__global__ __launch_bounds__(512, 2) void fused_mk(
    const float* __restrict__ A1, const float* __restrict__ A2,
    const float* __restrict__ F1, const float* __restrict__ F2,
    float* __restrict__ ws)
{
    __shared__ float f_lds[CHUNK_K * F_PAD];   // 36864 B
    __shared__ float c1_lds[NN];               // 32000 B  (total ~68.9 KB)

    const int bx  = blockIdx.x;
    const int mat = (bx >= 125) ? 1 : 0;
    const float* __restrict__ A = mat ? A2 : A1;
    const float* __restrict__ F = mat ? F2 : F1;
    float* __restrict__ c1 = ws + (mat ? WS_C1B : WS_C1A);
    float* __restrict__ M  = ws + (mat ? WS_M2 : WS_M1);
    const int row0 = (mat ? bx - 125 : bx) * 64;

    const int tid  = threadIdx.x;
    const int lane = tid & 63;
    const int wave = tid >> 6;
    const int kpos = lane & 15;
    const int lg   = lane >> 4;
    const int rbase = row0 + wave * 8;

    for (int i = tid; i < NN; i += 512) c1_lds[i] = 0.0f;

    float acc[8][8];
#pragma unroll
    for (int r = 0; r < 8; ++r)
#pragma unroll
        for (int e = 0; e < 8; ++e) acc[r][e] = 0.0f;

    const float* __restrict__ arow = A + (size_t)rbase * NN + kpos * 4;

    // prefetch iteration 0 (k0 = 0)
    float4 a_cur[8];
#pragma unroll
    for (int r = 0; r < 8; ++r)
        a_cur[r] = *(const float4*)(arow + (size_t)r * NN);

    const int slot = tid & 7;   // F staging: 8 threads per F row
    const int kcb  = tid >> 3;  // 0..63

    // 31 full chunks (k-iterations gi = 0..123), epilogue handles gi = 124
    for (int chunk = 0; chunk < 31; ++chunk) {
        const int ck = chunk * CHUNK_K;
#pragma unroll
        for (int j = 0; j < 4; ++j) {
            int kc = kcb + j * 64;
            float4 v = *(const float4*)(F + (size_t)(ck + kc) * LL + slot * 4);
            *(float4*)(f_lds + kc * F_PAD + slot * 4) = v;
        }
        __syncthreads();
#pragma unroll
        for (int it = 0; it < 4; ++it) {
            const int k0 = (chunk * 4 + it) * 64;
            // prefetch next iteration's A (gi+1 <= 124, always in range)
            float4 a_nxt[8];
#pragma unroll
            for (int r = 0; r < 8; ++r)
                a_nxt[r] = *(const float4*)(arow + (size_t)r * NN + k0 + 64);

            float4 csum = make_float4(0.f, 0.f, 0.f, 0.f);
            iter_math(a_cur, f_lds, it * 64 + kpos * 4, lg, acc, csum);
            if (lg == 0) {
                atomicAdd(&c1_lds[k0 + kpos * 4 + 0], csum.x);
                atomicAdd(&c1_lds[k0 + kpos * 4 + 1], csum.y);
                atomicAdd(&c1_lds[k0 + kpos * 4 + 2], csum.z);
                atomicAdd(&c1_lds[k0 + kpos * 4 + 3], csum.w);
            }
#pragma unroll
            for (int r = 0; r < 8; ++r) a_cur[r] = a_nxt[r];
        }
        __syncthreads();
    }
    // epilogue: ck = 7936, single iteration gi = 124 (a_cur already prefetched)
    {
        const int ck = 31 * CHUNK_K;   // 7936
#pragma unroll
        for (int j = 0; j < 4; ++j) {
            int kc = kcb + j * 64;
            int k = ck + kc;
            if (k < NN) {
                float4 v = *(const float4*)(F + (size_t)k * LL + slot * 4);
                *(float4*)(f_lds + kc * F_PAD + slot * 4) = v;
            }
        }
        __syncthreads();
        float4 csum = make_float4(0.f, 0.f, 0.f, 0.f);
        iter_math(a_cur, f_lds, kpos * 4, lg, acc, csum);
        if (lg == 0) {
            atomicAdd(&c1_lds[ck + kpos * 4 + 0], csum.x);
            atomicAdd(&c1_lds[ck + kpos * 4 + 1], csum.y);
            atomicAdd(&c1_lds[ck + kpos * 4 + 2], csum.z);
            atomicAdd(&c1_lds[ck + kpos * 4 + 3], csum.w);
        }
        __syncthreads();
    }

    // reduce acc across the 16 kpos lanes (lanes lg*16 .. lg*16+15)
#pragma unroll
    for (int r = 0; r < 8; ++r)
#pragma unroll
        for (int e = 0; e < 8; ++e) {
            float t = acc[r][e];
            t += __shfl_xor(t, 1);
            t += __shfl_xor(t, 2);
            t += __shfl_xor(t, 4);
            t += __shfl_xor(t, 8);
            acc[r][e] = t;
        }
    if (kpos == 0) {
#pragma unroll
        for (int r = 0; r < 8; ++r) {
            float* mp = M + (size_t)(rbase + r) * LL + lg * 8;
            *(float4*)(mp)     = make_float4(acc[r][0], acc[r][1], acc[r][2], acc[r][3]);
            *(float4*)(mp + 4) = make_float4(acc[r][4], acc[r][5], acc[r][6], acc[r][7]);
        }
    }
    // flush block's c1 partial (125 blocks/matrix hit each address)
    for (int i = tid; i < NN; i += 512)
        atomicAdd(&c1[i], c1_lds[i]);
}

// g-vectors: g_01 = colsum(F), g_h1 = colsum(M), g_h2 = c1^T M
// grid (8 row-chunks, 2 matrices), block 256 = 8 rows x 32 l.
__global__ void g_kernel(const float* __restrict__ F1, const float* __restrict__ F2,
                         float* __restrict__ ws)
{
    const int mat = blockIdx.y;
    const float* __restrict__ F  = mat ? F2 : F1;
    const float* __restrict__ Mw = ws + (mat ? WS_M2 : WS_M1);
    const float* __restrict__ c1 = ws + (mat ? WS_C1B : WS_C1A);
    float* __restrict__ g = ws + WS_G + mat * 96;

    int l  = threadIdx.x & 31;
    int ro = threadIdx.x >> 5;
    int i0 = blockIdx.x * 1000;
    float s0 = 0.f, s1 = 0.f, s2 = 0.f;
    for (int i = i0 + ro; i < i0 + 1000; i += 8) {
        s0 += F[(size_t)i * LL + l];
        float m = Mw[(size_t)i * LL + l];
        s1 += m;
        s2 += c1[i] * m;
    }
    __shared__ float red[3][256];
    red[0][threadIdx.x] = s0; red[1][threadIdx.x] = s1; red[2][threadIdx.x] = s2;
    __syncthreads();
    if (threadIdx.x < 32) {
        float t0 = 0.f, t1 = 0.f, t2 = 0.f;
        for (int r = 0; r < 8; ++r) {
            t0 += red[0][l + 32 * r];
            t1 += red[1][l + 32 * r];
            t2 += red[2][l + 32 * r];
        }
        atomicAdd(&g[0  + l], t0);
        atomicAdd(&g[32 + l], t1);
        atomicAdd(&g[64 + l], t2);
    }
}

// Head: 3 branches, one wave each. block = 192 threads.
// g layout: [g1_01 g1_h1 g1_h2 g2_01 g2_h1 g2_h2] (6 x 32)
// branch 0,1: x1 = g[0:64],  x2 = g[96:160]
// branch 2:   x1 = g[32:96], x2 = g[128:192]
__global__ void head_kernel(const float* __restrict__ g,
                            const float* __restrict__ tn_w,    // [3][64][64][16]
                            const float* __restrict__ tn_wb,   // [3][16][128]
                            const float* __restrict__ tn_bias, // [3][16]
                            const float* __restrict__ fc1_w,   // [3][16][16]
                            const float* __restrict__ fc1_b,
                            const float* __restrict__ fc2_w,   // [3][8][16]
                            const float* __restrict__ fc2_b,
                            const float* __restrict__ fc3_w,   // [3][4][8]
                            const float* __restrict__ fc3_b,
                            const float* __restrict__ sc_w,    // [3][1][4]
                            const float* __restrict__ sc_b,
                            float* __restrict__ out) {
    __shared__ float sg[192];
    __shared__ float sbuf[3][KK];
    int tid = threadIdx.x;
    sg[tid] = g[tid];
    __syncthreads();

    int br   = tid >> 6;        // 0..2
    int lane = tid & 63;

    int base1 = (br == 2) ? 32 : 0;
    int base2 = 96 + base1;
    float x2e = sg[base2 + lane];

    // bilin[k] = sum_e x2[e] * sum_d x1[d]*W[d][e][k];  lane == e
    float acc[KK];
#pragma unroll
    for (int k = 0; k < KK; ++k) acc[k] = 0.f;
    const float* wbase = tn_w + (size_t)br * DD * DD * KK + (size_t)lane * KK;
    for (int d = 0; d < DD; ++d) {
        float x1d = sg[base1 + d];
        const float4* wp4 = reinterpret_cast<const float4*>(wbase + (size_t)d * DD * KK);
#pragma unroll
        for (int q = 0; q < 4; ++q) {
            float4 v = wp4[q];
            acc[4*q+0] += x1d * v.x;
            acc[4*q+1] += x1d * v.y;
            acc[4*q+2] += x1d * v.z;
            acc[4*q+3] += x1d * v.w;
        }
    }
#pragma unroll
    for (int k = 0; k < KK; ++k) {
        float t = acc[k] * x2e;
#pragma unroll
        for (int off = 32; off >= 1; off >>= 1)
            t += __shfl_xor(t, off);
        acc[k] = t;
    }

    if (lane < KK) {
        const float* wb = tn_wb + (size_t)(br * KK + lane) * 2 * DD;
        float s = 0.f;
        for (int j = 0; j < DD; ++j) s += wb[j]      * sg[base1 + j];
        for (int j = 0; j < DD; ++j) s += wb[DD + j] * sg[base2 + j];
        s += acc[lane] + tn_bias[br * KK + lane];
        sbuf[br][lane] = fmaxf(s, 0.f);
    }
    __syncthreads();

    if (lane == 0) {
        float t1[BB], t2[8], t3[4];
        for (int b = 0; b < BB; ++b) {
            float s = fc1_b[br * BB + b];
            for (int k = 0; k < KK; ++k) s += fc1_w[(br * BB + b) * KK + k] * sbuf[br][k];
            t1[b] = fmaxf(s, 0.f);
        }
        for (int o = 0; o < 8; ++o) {
            float s = fc2_b[br * 8 + o];
            for (int b = 0; b < BB; ++b) s += fc2_w[(br * 8 + o) * BB + b] * t1[b];
            t2[o] = fmaxf(s, 0.f);
        }
        for (int q = 0; q < 4; ++q) {
            float s = fc3_b[br * 4 + q];
            for (int o = 0; o < 8; ++o) s += fc3_w[(br * 4 + q) * 8 + o] * t2[o];
            t3[q] = fmaxf(s, 0.f);
        }
        float s = sc_b[br];
        for (int q = 0; q < 4; ++q) s += sc_w[br * 4 + q] * t3[q];
        out[br] = 1.0f / (1.0f + expf(-s));
    }
}

extern "C" void kernel_launch(void* const* d_in, const int* in_sizes, int n_in,
                              void* d_out, int out_size, void* d_ws, size_t ws_size,
                              hipStream_t stream) {
    const float* adj1    = (const float*)d_in[0];
    const float* adj2    = (const float*)d_in[1];
    const float* feat1   = (const float*)d_in[2];
    const float* feat2   = (const float*)d_in[3];
    const float* tn_w    = (const float*)d_in[4];
    const float* tn_wb   = (const float*)d_in[5];
    const float* tn_bias = (const float*)d_in[6];
    const float* fc1_w   = (const float*)d_in[7];
    const float* fc1_b   = (const float*)d_in[8];
    const float* fc2_w   = (const float*)d_in[9];
    const float* fc2_b   = (const float*)d_in[10];
    const float* fc3_w   = (const float*)d_in[11];
    const float* fc3_b   = (const float*)d_in[12];
    const float* sc_w    = (const float*)d_in[13];
    const float* sc_b    = (const float*)d_in[14];

    float* ws  = (float*)d_ws;
    float* out = (float*)d_out;

    // 1. zero c1a, c1b, g (ws is poisoned 0xAA before every timed launch)
    zero_kernel<<<(WS_ZERO_N + 255) / 256, 256, 0, stream>>>(ws, WS_ZERO_N);

    // 2. single fused pass over both adjacencies: M = A@F and c1 = colsum(A)
    fused_mk<<<250, 512, 0, stream>>>(adj1, adj2, feat1, feat2, ws);

    // 3. g-vectors (reads F, M, c1 — all L2/L3 resident)
    g_kernel<<<dim3(8, 2), 256, 0, stream>>>(feat1, feat2, ws);

    // 4. head MLPs -> out[0..2]
    head_kernel<<<1, 192, 0, stream>>>(ws + WS_G, tn_w, tn_wb, tn_bias,
                                       fc1_w, fc1_b, fc2_w, fc2_b,
                                       fc3_w, fc3_b, sc_w, sc_b, out);
}